// Round 3
// baseline (6695.612 us; speedup 1.0000x reference)
//
#include <hip/hip_runtime.h>
#include <cstdint>

#define B_ 16
#define C_ 16
#define H_ 128
#define W_ 128
#define HID_ 128
#define NSTEPS 24
#define THR 0.1f
#define FRAMES 25
#define CHW (C_*H_*W_)
#define HW (H_*W_)
#define WSTR 80   // dwords per h-record: [48 w1 row | 16 w2t row | b1 | pad], 320B => 64B aligned rows

// frame 0 = input x, copied batch-wise into the strided output layout
__global__ void frame0_copy(const float4* __restrict__ x, float4* __restrict__ out) {
    int idx = blockIdx.x * 256 + threadIdx.x;      // over B*C*H*W/4 = 1,048,576
    int per_b = CHW / 4;
    int b = idx / per_b;
    int r = idx - b * per_b;
    out[(size_t)b * (FRAMES * CHW / 4) + r] = x[idx];
}

// interleaved weight records: wint[h][0..47]=w1 row h, [48..63]=w2[:,h], [64]=b1[h]
__global__ void wint_build(const float* __restrict__ w1, const float* __restrict__ b1,
                           const float* __restrict__ w2, float* __restrict__ wint) {
    int h = threadIdx.x;                            // 128 threads, 1 block
    float* r = wint + h * WSTR;
    for (int k = 0; k < 48; ++k) r[k] = w1[h * 48 + k];
    for (int c = 0; c < 16; ++c) r[48 + c] = w2[c * 128 + h];
    r[64] = b1[h];
}

// stepA: 8x8 pixel tile per block, 4 waves. Wave w computes h in [32w,32w+32)
// for all 64 pixels (conv redundant per wave), partial delta[16] per pixel,
// cross-wave LDS reduction, write UNMASKED x+delta to x1 and pre-life to premask.
__global__ __launch_bounds__(256) void stepA(
    const float* __restrict__ frames,   // d_out base
    const float* __restrict__ wint,     // (128, WSTR)
    float* __restrict__ x1,
    float* __restrict__ premask,
    int s)
{
    __shared__ float smem[4096];        // phase1: xs[16][10][10] (1600 f) ; phase2: dred[4][16][64]
    const int b = blockIdx.z;
    const int ty0 = blockIdx.y * 8, tx0 = blockIdx.x * 8;
    const int tid = threadIdx.x;
    const int p = tid & 63, wv = tid >> 6;
    const int py = p >> 3, px = p & 7;
    const float* xin = frames + ((size_t)b * FRAMES + s) * CHW;

    // cooperative halo load with wrap: 10x10 positions x 16 channels = 1600 floats
    #pragma unroll
    for (int i0 = 0; i0 < 1792; i0 += 256) {
        int i = i0 + tid;
        if (i < 1600) {
            int c = i / 100;
            int rem = i - c * 100;
            int iy = rem / 10, ix = rem - iy * 10;
            int gy = (ty0 + iy - 1) & (H_ - 1);
            int gx = (tx0 + ix - 1) & (W_ - 1);
            smem[i] = xin[c * HW + gy * W_ + gx];
        }
    }
    __syncthreads();

    // pre_life: 3x3 max over channel 0 of padded x (wave 0 writes it)
    const int pb = py * 10 + px;
    float m = -1e30f;
    #pragma unroll
    for (int dy = 0; dy < 3; ++dy)
        #pragma unroll
        for (int dx = 0; dx < 3; ++dx)
            m = fmaxf(m, smem[pb + dy * 10 + dx]);
    if (wv == 0)
        premask[b * HW + (ty0 + py) * W_ + tx0 + px] = (m > THR) ? 1.0f : 0.0f;

    // depthwise conv -> d[48], interleaved [id, sobel_x, sobel_y] per channel
    float d[48];
    #pragma unroll
    for (int c = 0; c < C_; ++c) {
        int base = c * 100 + pb;
        float a00 = smem[base],      a01 = smem[base + 1],  a02 = smem[base + 2];
        float a10 = smem[base + 10], a11 = smem[base + 11], a12 = smem[base + 12];
        float a20 = smem[base + 20], a21 = smem[base + 21], a22 = smem[base + 22];
        d[3 * c]     = a11;
        d[3 * c + 1] = (a02 - a00 + 2.0f * (a12 - a10) + a22 - a20) * 0.125f;
        d[3 * c + 2] = (a00 + 2.0f * a01 + a02 - a20 - 2.0f * a21 - a22) * 0.125f;
    }

    // 32 h-rows for this wave: partial delta accumulation
    float acc[16];
    #pragma unroll
    for (int c = 0; c < 16; ++c) acc[c] = 0.0f;

    const float* wb = wint + wv * 32 * WSTR;
    #pragma unroll 2
    for (int hh = 0; hh < 32; ++hh) {
        const float* wr = wb + hh * WSTR;
        float s0 = 0.f, s1 = 0.f, s2 = 0.f, s3 = 0.f;
        #pragma unroll
        for (int k = 0; k < 48; k += 4) {
            s0 = fmaf(wr[k + 0], d[k + 0], s0);
            s1 = fmaf(wr[k + 1], d[k + 1], s1);
            s2 = fmaf(wr[k + 2], d[k + 2], s2);
            s3 = fmaf(wr[k + 3], d[k + 3], s3);
        }
        float hv = fmaxf((s0 + s1) + (s2 + s3) + wr[64], 0.0f);
        #pragma unroll
        for (int c = 0; c < 16; ++c) acc[c] = fmaf(wr[48 + c], hv, acc[c]);
    }

    // cross-wave reduction: dred[wv][c][p] (bank = p mod 32 -> 2-way, free)
    __syncthreads();                    // all xs reads complete before overwrite
    #pragma unroll
    for (int c = 0; c < 16; ++c)
        smem[((wv * 16 + c) << 6) + p] = acc[c];
    __syncthreads();

    // each wave reduces 4 channels for its pixel p; d[] is for pixel p in every wave
    float* xo = x1 + (size_t)b * CHW + (ty0 + py) * W_ + tx0 + px;
    #pragma unroll
    for (int j = 0; j < 4; ++j) {
        int c = (wv << 2) + j;
        float v = smem[(c << 6) + p] + smem[((16 + c) << 6) + p]
                + smem[((32 + c) << 6) + p] + smem[((48 + c) << 6) + p];
        xo[c * HW] = d[3 * c] + v;      // d[3c] is the identity tap = old x
    }
}

// stepB: post-life on unmasked x1 channel 0 (wrap), combine with pre-life,
// write masked state as frame s+1.
__global__ __launch_bounds__(256) void stepB(
    const float* __restrict__ x1,
    const float* __restrict__ premask,
    float* __restrict__ frames,
    int s)
{
    int idx = blockIdx.x * 256 + threadIdx.x;   // over B*H*W = 262144
    int b = idx >> 14;
    int yx = idx & (HW - 1);
    int y = yx >> 7, x = yx & (W_ - 1);
    const float* c0 = x1 + (size_t)b * CHW;
    float m = -1e30f;
    #pragma unroll
    for (int dy = -1; dy <= 1; ++dy) {
        int gy = (y + dy) & (H_ - 1);
        #pragma unroll
        for (int dx = -1; dx <= 1; ++dx) {
            int gx = (x + dx) & (W_ - 1);
            m = fmaxf(m, c0[gy * W_ + gx]);
        }
    }
    float life = (m > THR && premask[idx] != 0.0f) ? 1.0f : 0.0f;
    const float* xi = x1 + (size_t)b * CHW + yx;
    float* xo = frames + ((size_t)b * FRAMES + s + 1) * CHW + yx;
    #pragma unroll
    for (int c = 0; c < C_; ++c)
        xo[c * HW] = xi[c * HW] * life;
}

extern "C" void kernel_launch(void* const* d_in, const int* in_sizes, int n_in,
                              void* d_out, int out_size, void* d_ws, size_t ws_size,
                              hipStream_t stream)
{
    const float* x  = (const float*)d_in[0];
    const float* w1 = (const float*)d_in[1];
    const float* b1 = (const float*)d_in[2];
    const float* w2 = (const float*)d_in[3];
    // d_in[4] = steps (fixed at 24 for this problem)
    float* out = (float*)d_out;

    float* x1      = (float*)d_ws;                                        // 16 MB
    float* premask = (float*)((char*)d_ws + (size_t)B_ * CHW * 4);        // 1 MB
    float* wint    = (float*)((char*)d_ws + (size_t)B_ * CHW * 4 + (size_t)B_ * HW * 4);  // 40 KB

    wint_build<<<1, 128, 0, stream>>>(w1, b1, w2, wint);
    frame0_copy<<<(B_ * CHW / 4) / 256, 256, 0, stream>>>((const float4*)x, (float4*)out);

    for (int s = 0; s < NSTEPS; ++s) {
        stepA<<<dim3(W_ / 8, H_ / 8, B_), 256, 0, stream>>>(out, wint, x1, premask, s);
        stepB<<<(B_ * HW) / 256, 256, 0, stream>>>(x1, premask, out, s);
    }
}

// Round 4
// 3293.559 us; speedup vs baseline: 2.0329x; 2.0329x over previous
//
#include <hip/hip_runtime.h>
#include <cstdint>

#define B_ 16
#define C_ 16
#define H_ 128
#define W_ 128
#define HID_ 128
#define NSTEPS 24
#define THR 0.1f
#define FRAMES 25
#define CHW (C_*H_*W_)
#define HW (H_*W_)
#define WSTR 80   // dwords per h-record: [48 w1 row | 16 w2 col | b1 | pad], 320B, 64B-aligned

// LDS tile geometry: 2x32 output tile, 4x34 halo, row stride 36 (banks 0,4,8,12 -> 2-way, free)
#define HLO_W 34
#define HLO_H 4
#define ROWS 36
#define CSTR (HLO_H*ROWS)   // 144
#define NHALO (HLO_W*HLO_H) // 136

// frame 0 = input x, copied batch-wise into the strided output layout
__global__ void frame0_copy(const float4* __restrict__ x, float4* __restrict__ out) {
    int idx = blockIdx.x * 256 + threadIdx.x;      // over B*C*H*W/4 = 1,048,576
    int per_b = CHW / 4;
    int b = idx / per_b;
    int r = idx - b * per_b;
    out[(size_t)b * (FRAMES * CHW / 4) + r] = x[idx];
}

// interleaved weight records: wint[h][0..47]=w1 row h, [48..63]=w2[:,h], [64]=b1[h]
__global__ void wint_build(const float* __restrict__ w1, const float* __restrict__ b1,
                           const float* __restrict__ w2, float* __restrict__ wint) {
    int h = threadIdx.x;                            // 128 threads, 1 block
    float* r = wint + h * WSTR;
    for (int k = 0; k < 48; ++k) r[k] = w1[h * 48 + k];
    for (int c = 0; c < 16; ++c) r[48 + c] = w2[c * 128 + h];
    r[64] = b1[h];
}

// stepA: 2x32 pixel tile per block, 4 waves. Wave wv computes h in [32wv,32wv+32)
// for all 64 pixels (conv redundant per wave), partial delta[16] per pixel,
// cross-wave LDS reduction, write UNMASKED x+delta to x1 and pre-life to premask.
// Weight base forced to SGPR via readfirstlane -> s_load weight stream.
__global__ __launch_bounds__(256) void stepA(
    const float* __restrict__ frames,   // d_out base
    const float* __restrict__ wint,     // (128, WSTR)
    float* __restrict__ x1,
    float* __restrict__ premask,
    int s)
{
    __shared__ float smem[4096];        // phase1: xs[16][4][36] (2304 f); phase2: dred[4][16][64]

    // chunked XCD swizzle: 4096 blocks = 8 XCDs x 512; XCD k owns 2 whole images
    int id = blockIdx.x;
    int work = (id & 7) * 512 + (id >> 3);
    const int b = work >> 8;            // 0..15
    int rem = work & 255;
    const int ty0 = (rem >> 2) * 2;     // 0,2,..,126
    const int tx0 = (rem & 3) * 32;     // 0,32,64,96

    const int tid = threadIdx.x;
    const int p = tid & 63, wv = tid >> 6;
    const int py = p >> 5, px = p & 31; // 2 rows x 32 cols
    const float* xin = frames + ((size_t)b * FRAMES + s) * CHW;

    // cooperative halo load with wrap: 4x34 positions x 16 channels = 2176 floats
    for (int i = tid; i < C_ * NHALO; i += 256) {
        int c = i / NHALO;
        int r2 = i - c * NHALO;
        int iy = r2 / HLO_W, ix = r2 - iy * HLO_W;
        int gy = (ty0 + iy - 1) & (H_ - 1);
        int gx = (tx0 + ix - 1) & (W_ - 1);
        smem[c * CSTR + iy * ROWS + ix] = xin[c * HW + gy * W_ + gx];
    }
    __syncthreads();

    // pre_life: 3x3 max over channel 0 of padded x (wave 0 writes it)
    const int pb = py * ROWS + px;
    float m = -1e30f;
    #pragma unroll
    for (int dy = 0; dy < 3; ++dy)
        #pragma unroll
        for (int dx = 0; dx < 3; ++dx)
            m = fmaxf(m, smem[pb + dy * ROWS + dx]);
    if (wv == 0)
        premask[b * HW + (ty0 + py) * W_ + tx0 + px] = (m > THR) ? 1.0f : 0.0f;

    // depthwise conv -> d[48], interleaved [id, sobel_x, sobel_y] per channel
    float d[48];
    #pragma unroll
    for (int c = 0; c < C_; ++c) {
        int base = c * CSTR + pb;
        float a00 = smem[base],            a01 = smem[base + 1],        a02 = smem[base + 2];
        float a10 = smem[base + ROWS],     a11 = smem[base + ROWS + 1], a12 = smem[base + ROWS + 2];
        float a20 = smem[base + 2 * ROWS], a21 = smem[base + 2 * ROWS + 1], a22 = smem[base + 2 * ROWS + 2];
        d[3 * c]     = a11;
        d[3 * c + 1] = (a02 - a00 + 2.0f * (a12 - a10) + a22 - a20) * 0.125f;
        d[3 * c + 2] = (a00 + 2.0f * a01 + a02 - a20 - 2.0f * a21 - a22) * 0.125f;
    }

    // 32 h-rows for this wave: partial delta accumulation.
    // readfirstlane forces the base index into an SGPR -> scalar weight loads.
    float acc[16];
    #pragma unroll
    for (int c = 0; c < 16; ++c) acc[c] = 0.0f;

    const int hbase = __builtin_amdgcn_readfirstlane(wv << 5);
    const float* wb = wint + hbase * WSTR;
    for (int hh = 0; hh < 32; ++hh) {
        const float* wr = wb + hh * WSTR;
        float s0 = 0.f, s1 = 0.f, s2 = 0.f, s3 = 0.f;
        #pragma unroll
        for (int k = 0; k < 48; k += 4) {
            s0 = fmaf(wr[k + 0], d[k + 0], s0);
            s1 = fmaf(wr[k + 1], d[k + 1], s1);
            s2 = fmaf(wr[k + 2], d[k + 2], s2);
            s3 = fmaf(wr[k + 3], d[k + 3], s3);
        }
        float hv = fmaxf((s0 + s1) + (s2 + s3) + wr[64], 0.0f);
        #pragma unroll
        for (int c = 0; c < 16; ++c) acc[c] = fmaf(wr[48 + c], hv, acc[c]);
    }

    // cross-wave reduction: dred[wv][c][p] (bank = p mod 32 -> 2-way, free)
    __syncthreads();                    // all xs reads complete before overwrite
    #pragma unroll
    for (int c = 0; c < 16; ++c)
        smem[((wv * 16 + c) << 6) + p] = acc[c];
    __syncthreads();

    // each wave reduces 4 channels for its pixel p; d[] is valid for pixel p in every wave
    float* xo = x1 + (size_t)b * CHW + (ty0 + py) * W_ + tx0 + px;
    #pragma unroll
    for (int j = 0; j < 4; ++j) {
        int c = (wv << 2) + j;
        float v = smem[(c << 6) + p] + smem[((16 + c) << 6) + p]
                + smem[((32 + c) << 6) + p] + smem[((48 + c) << 6) + p];
        xo[c * HW] = d[3 * c] + v;      // d[3c] is the identity tap = old x
    }
}

// stepB: post-life on unmasked x1 channel 0 (wrap), combine with pre-life,
// write masked state as frame s+1.
__global__ __launch_bounds__(256) void stepB(
    const float* __restrict__ x1,
    const float* __restrict__ premask,
    float* __restrict__ frames,
    int s)
{
    int idx = blockIdx.x * 256 + threadIdx.x;   // over B*H*W = 262144
    int b = idx >> 14;
    int yx = idx & (HW - 1);
    int y = yx >> 7, x = yx & (W_ - 1);
    const float* c0 = x1 + (size_t)b * CHW;
    float m = -1e30f;
    #pragma unroll
    for (int dy = -1; dy <= 1; ++dy) {
        int gy = (y + dy) & (H_ - 1);
        #pragma unroll
        for (int dx = -1; dx <= 1; ++dx) {
            int gx = (x + dx) & (W_ - 1);
            m = fmaxf(m, c0[gy * W_ + gx]);
        }
    }
    float life = (m > THR && premask[idx] != 0.0f) ? 1.0f : 0.0f;
    const float* xi = x1 + (size_t)b * CHW + yx;
    float* xo = frames + ((size_t)b * FRAMES + s + 1) * CHW + yx;
    #pragma unroll
    for (int c = 0; c < C_; ++c)
        xo[c * HW] = xi[c * HW] * life;
}

extern "C" void kernel_launch(void* const* d_in, const int* in_sizes, int n_in,
                              void* d_out, int out_size, void* d_ws, size_t ws_size,
                              hipStream_t stream)
{
    const float* x  = (const float*)d_in[0];
    const float* w1 = (const float*)d_in[1];
    const float* b1 = (const float*)d_in[2];
    const float* w2 = (const float*)d_in[3];
    // d_in[4] = steps (fixed at 24 for this problem)
    float* out = (float*)d_out;

    float* x1      = (float*)d_ws;                                        // 16 MB
    float* premask = (float*)((char*)d_ws + (size_t)B_ * CHW * 4);        // 1 MB
    float* wint    = (float*)((char*)d_ws + (size_t)B_ * CHW * 4 + (size_t)B_ * HW * 4);  // 40 KB

    wint_build<<<1, 128, 0, stream>>>(w1, b1, w2, wint);
    frame0_copy<<<(B_ * CHW / 4) / 256, 256, 0, stream>>>((const float4*)x, (float4*)out);

    for (int s = 0; s < NSTEPS; ++s) {
        stepA<<<4096, 256, 0, stream>>>(out, wint, x1, premask, s);
        stepB<<<(B_ * HW) / 256, 256, 0, stream>>>(x1, premask, out, s);
    }
}